// Round 6
// baseline (41.368 us; speedup 1.0000x reference)
//
#include <hip/hip_runtime.h>
#include <math.h>

#define N_   256
#define B_   256
#define DM   1024
#define KH   1280   // n*5
#define PI24 0.13089969389957473f
#define SPLITS 2
#define KC    640   // K per split

// ws layout (floats):
//   wT    : [0, 131072)            65536 float2 (w0, relu(S)) transposed [j][i]
//   Hp    : [131072, +2*262144)    split-K partials (fp32)
//   histB : [655360, +163840)      256x1280 bf16
//   W1T   : [819200, +655360)      1024x1280 bf16 (transposed)
#define WS_WT    0
#define WS_PART  131072
#define WS_HISTB 655360
#define WS_W1T   819200

typedef __attribute__((ext_vector_type(8))) short short8;
typedef __attribute__((ext_vector_type(4))) float f32x4;

__device__ inline unsigned short f2bf(float f) {
    unsigned int u = __float_as_uint(f);
    u += 0x7fffu + ((u >> 16) & 1u);   // round-to-nearest-even
    return (unsigned short)(u >> 16);
}

// ---------------------------------------------------------------------------
// K0: blocks 0..79    : hist fp32 -> bf16 (same layout)
//     blocks 80..399  : W1 fp32 [k][n] -> W1T bf16 [n][k]  (64x64 LDS tiles)
//     blocks 400..463 : prep  w0 = sigmoid(p0-p1), s = relu(S) -> wT[j][i]
// ---------------------------------------------------------------------------
__global__ __launch_bounds__(512, 4) void k0_convert(
    const float* __restrict__ hist, const float* __restrict__ W1,
    const float* __restrict__ pw,   const float* __restrict__ S,
    float* __restrict__ ws) {
    __shared__ union {
        float  t64[64][65];
        float2 ptile[32][33];
    } sh;

    unsigned short* histB = (unsigned short*)(ws + WS_HISTB);
    unsigned short* W1T   = (unsigned short*)(ws + WS_W1T);
    float2*         wT    = (float2*)(ws + WS_WT);

    int bid = blockIdx.x, tid = threadIdx.x;

    if (bid < 80) {                       // ---- hist convert ----
        int idx = bid * 4096 + tid * 8;
        float4 v0 = *(const float4*)&hist[idx];
        float4 v1 = *(const float4*)&hist[idx + 4];
        float v[8] = {v0.x, v0.y, v0.z, v0.w, v1.x, v1.y, v1.z, v1.w};
        short8 o;
#pragma unroll
        for (int e = 0; e < 8; e++) o[e] = (short)f2bf(v[e]);
        *(short8*)&histB[idx] = o;
    } else if (bid < 400) {               // ---- W1 transpose+convert ----
        int tb = bid - 80;
        int k0t = (tb >> 4) * 64, n0t = (tb & 15) * 64;
#pragma unroll
        for (int rep = 0; rep < 2; ++rep) {
            int r = rep * 32 + (tid >> 4), c = (tid & 15) * 4;
            float4 v = *(const float4*)&W1[(k0t + r) * DM + n0t + c];
            sh.t64[r][c] = v.x; sh.t64[r][c + 1] = v.y;
            sh.t64[r][c + 2] = v.z; sh.t64[r][c + 3] = v.w;
        }
        __syncthreads();
        int rr = tid >> 3, cc = (tid & 7) * 8;
        short8 o;
#pragma unroll
        for (int j = 0; j < 8; j++) o[j] = (short)f2bf(sh.t64[cc + j][rr]);
        *(short8*)&W1T[(n0t + rr) * KH + k0t + cc] = o;
    } else {                              // ---- prep ----
        int pb = bid - 400;
        int i0 = (pb >> 3) * 32, j0 = (pb & 7) * 32;
#pragma unroll
        for (int rep = 0; rep < 2; ++rep) {
            int idx = rep * 512 + tid;
            int r = idx >> 5, c = idx & 31;          // r: local i, c: local j
            float2 p = *(const float2*)&pw[((i0 + r) * N_ + j0 + c) * 2];
            float sv = S[(i0 + r) * N_ + j0 + c];
            float w0 = 1.f / (1.f + __expf(p.y - p.x));
            sh.ptile[r][c] = make_float2(w0, fmaxf(sv, 0.f));
        }
        __syncthreads();
#pragma unroll
        for (int rep = 0; rep < 2; ++rep) {
            int idx = rep * 512 + tid;
            int r = idx >> 5, c = idx & 31;          // r: local j, c: local i
            wT[(j0 + r) * N_ + i0 + c] = sh.ptile[c][r];
        }
    }
}

// ---------------------------------------------------------------------------
// K1: bf16 MFMA GEMM, fragments straight from global (L2-resident operands).
// 64 tiles (4Mx16N of 64x64) x 2 K-splits; 8 waves = 2(M)x4(N), each wave a
// 32x16 sub-tile: per 32-k step {3 dwordx4 loads, 2 MFMA}. No LDS/barriers.
// ---------------------------------------------------------------------------
__global__ __launch_bounds__(512, 4) void k1_gemm(
    const float* __restrict__ ws_ro, float* __restrict__ ws) {
    const unsigned short* histB = (const unsigned short*)(ws_ro + WS_HISTB);
    const unsigned short* W1T   = (const unsigned short*)(ws_ro + WS_W1T);
    float* Hp = ws + WS_PART;

    int bid = blockIdx.x, tid = threadIdx.x;
    int t64 = bid & 63, ksp = bid >> 6;
    int m0 = (t64 >> 4) * 64, n0 = (t64 & 15) * 64;
    int kbase = ksp * KC;

    int lane = tid & 63, wv = tid >> 6;
    int wrow = wv & 1, wcol = wv >> 1;
    int l16 = lane & 15, lk8 = (lane >> 4) * 8;

    const unsigned short* aP = &histB[(m0 + wrow * 32 + l16) * KH + kbase + lk8];
    const unsigned short* bP = &W1T[(n0 + wcol * 16 + l16) * KH + kbase + lk8];

    f32x4 acc0 = {0.f, 0.f, 0.f, 0.f};
    f32x4 acc1 = {0.f, 0.f, 0.f, 0.f};

#pragma unroll 4
    for (int k = 0; k < KC; k += 32) {
        short8 a0 = *(const short8*)(aP + k);
        short8 a1 = *(const short8*)(aP + k + 16 * KH);
        short8 bf = *(const short8*)(bP + k);
        acc0 = __builtin_amdgcn_mfma_f32_16x16x32_bf16(a0, bf, acc0, 0, 0, 0);
        acc1 = __builtin_amdgcn_mfma_f32_16x16x32_bf16(a1, bf, acc1, 0, 0, 0);
    }
    {   // store fp32 partials: D row=(lane>>4)*4+reg, col=lane&15
        float* P = Hp + (size_t)ksp * (B_ * DM);
        int prow = (lane >> 4) * 4;
        int pcol = n0 + wcol * 16 + l16;
#pragma unroll
        for (int r = 0; r < 4; r++) {
            P[(m0 + wrow * 32 + prow + r) * DM + pcol]      = acc0[r];
            P[(m0 + wrow * 32 + 16 + prow + r) * DM + pcol] = acc1[r];
        }
    }
}

// ---------------------------------------------------------------------------
// K2: head (sum 2 partials, LN, ReLU, W2, tanh/sigmoid -> LDS consts) + main.
// One block per batch, 512 threads.
// ---------------------------------------------------------------------------
__global__ __launch_bounds__(512, 4) void k2_head_main(
    const float* __restrict__ ws_ro, const float* __restrict__ b1,
    const float* __restrict__ lg, const float* __restrict__ lb,
    const float* __restrict__ W2, const float* __restrict__ b2,
    const float* __restrict__ phi_prev, const float* __restrict__ x2,
    float* __restrict__ out) {
    __shared__ float2 hred2[8];
    __shared__ float4 hred4[8];
    __shared__ float  cbc[8];
    __shared__ float2 xs[256];
    __shared__ float2 sred[256];

    const float2* wT = (const float2*)(ws_ro + WS_WT);
    const float*  Hp = ws_ro + WS_PART;

    int b = blockIdx.x;
    int tid = threadIdx.x;
    int lane = tid & 63, wid = tid >> 6;

    ((float*)xs)[tid] = x2[b * (N_ * 2) + tid];

    // ---- head ----
    float2 b12 = *(const float2*)&b1[tid * 2];
    float h0 = b12.x, h1 = b12.y;
#pragma unroll
    for (int s = 0; s < SPLITS; ++s) {
        float2 p = *(const float2*)&Hp[(size_t)s * (B_ * DM) + b * DM + tid * 2];
        h0 += p.x; h1 += p.y;
    }
    float s1v = h0 + h1, s2v = h0 * h0 + h1 * h1;
#pragma unroll
    for (int off = 32; off > 0; off >>= 1) {
        s1v += __shfl_down(s1v, off);
        s2v += __shfl_down(s2v, off);
    }
    if (lane == 0) hred2[wid] = make_float2(s1v, s2v);
    __syncthreads();
    float ms = 0.f, vs = 0.f;
#pragma unroll
    for (int w = 0; w < 8; ++w) { ms += hred2[w].x; vs += hred2[w].y; }
    float mean = ms * (1.f / DM);
    float var  = vs * (1.f / DM) - mean * mean;
    float rstd = rsqrtf(var + 1e-5f);

    float2 g2  = *(const float2*)&lg[tid * 2];
    float2 be2 = *(const float2*)&lb[tid * 2];
    float y0 = fmaxf((h0 - mean) * rstd * g2.x + be2.x, 0.f);
    float y1 = fmaxf((h1 - mean) * rstd * g2.y + be2.y, 0.f);
    float4 wA = *(const float4*)&W2[(tid * 2) * 4];
    float4 wB = *(const float4*)&W2[(tid * 2 + 1) * 4];
    float4 pv;
    pv.x = y0 * wA.x + y1 * wB.x;
    pv.y = y0 * wA.y + y1 * wB.y;
    pv.z = y0 * wA.z + y1 * wB.z;
    pv.w = y0 * wA.w + y1 * wB.w;
#pragma unroll
    for (int off = 32; off > 0; off >>= 1) {
        pv.x += __shfl_down(pv.x, off);
        pv.y += __shfl_down(pv.y, off);
        pv.z += __shfl_down(pv.z, off);
        pv.w += __shfl_down(pv.w, off);
    }
    if (lane == 0) hred4[wid] = pv;
    __syncthreads();
    if (tid == 0) {
        float P0 = b2[0], P1 = b2[1], P2 = b2[2], P3 = b2[3];
#pragma unroll
        for (int w = 0; w < 8; ++w) {
            float4 o = hred4[w];
            P0 += o.x; P1 += o.y; P2 += o.z; P3 += o.w;
        }
        float dphi0 = tanhf(P0) * PI24;
        float dphi1 = tanhf(P2) * PI24;
        float phi0 = phi_prev[b * 2 + 0] + dphi0;
        float phi1 = phi_prev[b * 2 + 1] + dphi1;
        float r0 = 1.f / (1.f + expf(-P1));
        float r1 = 1.f / (1.f + expf(-P3));
        out[B_ * N_ * 2 + b * 2 + 0] = phi0;
        out[B_ * N_ * 2 + b * 2 + 1] = phi1;
        out[B_ * N_ * 2 + B_ * 2 + b * 2 + 0] = dphi0;
        out[B_ * N_ * 2 + B_ * 2 + b * 2 + 1] = dphi1;
        cbc[0] = phi0 - phi1;   // delta
        cbc[1] = r1;
        cbc[2] = r0 - r1;       // dr
        cbc[3] = cosf(phi1);
        cbc[4] = sinf(phi1);
    }
    __syncthreads();
    float delta = cbc[0], r1v = cbc[1], drv = cbc[2], c1 = cbc[3], sn1 = cbc[4];

    int i = tid & 255, jh = tid >> 8;
    int jbase = jh * 128;
    const float2* wp = &wT[jbase * N_ + i];

    float ar0 = 0.f, ai0 = 0.f, ar1 = 0.f, ai1 = 0.f;
#pragma unroll 4
    for (int jj = 0; jj < 128; jj += 2) {
        {
            float2 w = wp[(size_t)jj * N_];
            float r = fmaf(w.x, drv, r1v);
            float g = r * w.y;                       // in (0, 0.4)
            float u = g * g;
            // 1.1*tanh(g) = g*(1.1 + u*(-1.1/3 + u*(2.2/15 - u*1.1*17/315)))
            float tp = fmaf(u, fmaf(u, fmaf(u, -0.059365079f, 0.14666667f),
                                    -0.36666667f), 1.1f);
            float A = g * tp;
            float ang = w.x * delta;
            float sn = __sinf(ang);
            float cs = __cosf(ang);
            float2 xv = xs[jbase + jj];
            float ar = A * cs, as_ = A * sn;
            ar0 = fmaf(ar, xv.x, ar0); ar0 = fmaf(-as_, xv.y, ar0);
            ai0 = fmaf(as_, xv.x, ai0); ai0 = fmaf(ar, xv.y, ai0);
        }
        {
            float2 w = wp[(size_t)(jj + 1) * N_];
            float r = fmaf(w.x, drv, r1v);
            float g = r * w.y;
            float u = g * g;
            float tp = fmaf(u, fmaf(u, fmaf(u, -0.059365079f, 0.14666667f),
                                    -0.36666667f), 1.1f);
            float A = g * tp;
            float ang = w.x * delta;
            float sn = __sinf(ang);
            float cs = __cosf(ang);
            float2 xv = xs[jbase + jj + 1];
            float ar = A * cs, as_ = A * sn;
            ar1 = fmaf(ar, xv.x, ar1); ar1 = fmaf(-as_, xv.y, ar1);
            ai1 = fmaf(as_, xv.x, ai1); ai1 = fmaf(ar, xv.y, ai1);
        }
    }
    float accr = ar0 + ar1, acci = ai0 + ai1;
    if (jh) sred[i] = make_float2(accr, acci);
    __syncthreads();
    if (!jh) {
        float2 o = sred[i];
        accr += o.x; acci += o.y;
        float outr = c1 * accr - sn1 * acci;
        float outi = sn1 * accr + c1 * acci;
        ((float2*)out)[b * N_ + i] = make_float2(outr, outi);
    }
}

// ---------------------------------------------------------------------------
extern "C" void kernel_launch(void* const* d_in, const int* in_sizes, int n_in,
                              void* d_out, int out_size, void* d_ws, size_t ws_size,
                              hipStream_t stream) {
    const float* x_2ch    = (const float*)d_in[0];
    const float* history  = (const float*)d_in[1];
    const float* phi_prev = (const float*)d_in[2];
    const float* S        = (const float*)d_in[3];
    const float* W1       = (const float*)d_in[4];
    const float* b1       = (const float*)d_in[5];
    const float* ln_g     = (const float*)d_in[6];
    const float* ln_b     = (const float*)d_in[7];
    const float* W2       = (const float*)d_in[8];
    const float* b2       = (const float*)d_in[9];
    const float* path_w   = (const float*)d_in[10];

    float* out = (float*)d_out;
    float* ws  = (float*)d_ws;

    k0_convert  <<<464, 512, 0, stream>>>(history, W1, path_w, S, ws);
    k1_gemm     <<<128, 512, 0, stream>>>(ws, ws);
    k2_head_main<<<256, 512, 0, stream>>>(ws, b1, ln_g, ln_b, W2, b2,
                                          phi_prev, x_2ch, out);
}

// Round 7
// 33.452 us; speedup vs baseline: 1.2366x; 1.2366x over previous
//
#include <hip/hip_runtime.h>
#include <math.h>

#define N_   256
#define B_   256
#define DM   1024
#define KH   1280   // n*5
#define PI24 0.13089969389957473f
#define SPLITS 4
#define KC    320   // K per split
#define NSUB  5     // KC / 64

// ws layout (floats):
//   wT    : [0, 131072)            65536 float2 (w0, relu(S)) transposed [j][i]
//   Hp    : [131072, +4*262144)    split-K partials (fp32)
//   histB : [1179648, +163840)     256x1280 bf16
//   W1T   : [1343488, +655360)     1024x1280 bf16 (transposed)
#define WS_WT    0
#define WS_PART  131072
#define WS_HISTB 1179648
#define WS_W1T   1343488

typedef __attribute__((ext_vector_type(8))) short short8;
typedef __attribute__((ext_vector_type(4))) float f32x4;

__device__ inline unsigned short f2bf(float f) {
    unsigned int u = __float_as_uint(f);
    u += 0x7fffu + ((u >> 16) & 1u);   // round-to-nearest-even
    return (unsigned short)(u >> 16);
}

// ---------------------------------------------------------------------------
// K0: blocks 0..79    : hist fp32 -> bf16 (same layout)
//     blocks 80..399  : W1 fp32 [k][n] -> W1T bf16 [n][k]  (64x64 LDS tiles)
//     blocks 400..463 : prep  w0 = sigmoid(p0-p1), s = relu(S) -> wT[j][i]
// ---------------------------------------------------------------------------
__global__ __launch_bounds__(512, 4) void k0_convert(
    const float* __restrict__ hist, const float* __restrict__ W1,
    const float* __restrict__ pw,   const float* __restrict__ S,
    float* __restrict__ ws) {
    __shared__ union {
        float  t64[64][65];
        float2 ptile[32][33];
    } sh;

    unsigned short* histB = (unsigned short*)(ws + WS_HISTB);
    unsigned short* W1T   = (unsigned short*)(ws + WS_W1T);
    float2*         wT    = (float2*)(ws + WS_WT);

    int bid = blockIdx.x, tid = threadIdx.x;

    if (bid < 80) {                       // ---- hist convert ----
        int idx = bid * 4096 + tid * 8;
        float4 v0 = *(const float4*)&hist[idx];
        float4 v1 = *(const float4*)&hist[idx + 4];
        float v[8] = {v0.x, v0.y, v0.z, v0.w, v1.x, v1.y, v1.z, v1.w};
        short8 o;
#pragma unroll
        for (int e = 0; e < 8; e++) o[e] = (short)f2bf(v[e]);
        *(short8*)&histB[idx] = o;
    } else if (bid < 400) {               // ---- W1 transpose+convert ----
        int tb = bid - 80;
        int k0t = (tb >> 4) * 64, n0t = (tb & 15) * 64;
#pragma unroll
        for (int rep = 0; rep < 2; ++rep) {
            int r = rep * 32 + (tid >> 4), c = (tid & 15) * 4;
            float4 v = *(const float4*)&W1[(k0t + r) * DM + n0t + c];
            sh.t64[r][c] = v.x; sh.t64[r][c + 1] = v.y;
            sh.t64[r][c + 2] = v.z; sh.t64[r][c + 3] = v.w;
        }
        __syncthreads();
        int rr = tid >> 3, cc = (tid & 7) * 8;
        short8 o;
#pragma unroll
        for (int j = 0; j < 8; j++) o[j] = (short)f2bf(sh.t64[cc + j][rr]);
        *(short8*)&W1T[(n0t + rr) * KH + k0t + cc] = o;
    } else {                              // ---- prep ----
        int pb = bid - 400;
        int i0 = (pb >> 3) * 32, j0 = (pb & 7) * 32;
#pragma unroll
        for (int rep = 0; rep < 2; ++rep) {
            int idx = rep * 512 + tid;
            int r = idx >> 5, c = idx & 31;          // r: local i, c: local j
            float2 p = *(const float2*)&pw[((i0 + r) * N_ + j0 + c) * 2];
            float sv = S[(i0 + r) * N_ + j0 + c];
            float w0 = 1.f / (1.f + __expf(p.y - p.x));
            sh.ptile[r][c] = make_float2(w0, fmaxf(sv, 0.f));
        }
        __syncthreads();
#pragma unroll
        for (int rep = 0; rep < 2; ++rep) {
            int idx = rep * 512 + tid;
            int r = idx >> 5, c = idx & 31;          // r: local j, c: local i
            wT[(j0 + r) * N_ + i0 + c] = sh.ptile[c][r];
        }
    }
}

// ---------------------------------------------------------------------------
// K1: bf16 MFMA GEMM with LDS staging (coalesced global reads, no cvt).
// 64 tiles (4Mx16N of 64x64) x 4 K-splits = 256 blocks; 8 waves = 2(M)x4(N),
// each wave a 32x16 sub-tile: 4 MFMA per 64-k substep.
// ---------------------------------------------------------------------------
__global__ __launch_bounds__(512, 4) void k1_gemm(
    const float* __restrict__ ws_ro, float* __restrict__ ws) {
    __shared__ unsigned short As[64][72];   // [m][k] bf16, stride 72
    __shared__ unsigned short Bs[64][72];   // [n][k] bf16

    const unsigned short* histB = (const unsigned short*)(ws_ro + WS_HISTB);
    const unsigned short* W1T   = (const unsigned short*)(ws_ro + WS_W1T);
    float* Hp = ws + WS_PART;

    int bid = blockIdx.x, tid = threadIdx.x;
    int t64 = bid & 63, ksp = bid >> 6;
    int m0 = (t64 >> 4) * 64, n0 = (t64 & 15) * 64;
    int kbase = ksp * KC;

    int lane = tid & 63, wv = tid >> 6;
    int wrow = wv & 1, wcol = wv >> 1;
    int l16 = lane & 15, lk8 = (lane >> 4) * 8;
    int sRow = tid >> 3, sCol = (tid & 7) * 8;    // staging: 64 rows x 64 k

    short8 aReg = *(const short8*)&histB[(m0 + sRow) * KH + kbase + sCol];
    short8 bReg = *(const short8*)&W1T[(n0 + sRow) * KH + kbase + sCol];

    f32x4 acc0 = {0.f, 0.f, 0.f, 0.f};
    f32x4 acc1 = {0.f, 0.f, 0.f, 0.f};

    for (int s = 0; s < NSUB; ++s) {
        __syncthreads();   // previous compute done -> LDS writable
        *(short8*)&As[sRow][sCol] = aReg;
        *(short8*)&Bs[sRow][sCol] = bReg;
        if (s + 1 < NSUB) {
            int kb = kbase + (s + 1) * 64;
            aReg = *(const short8*)&histB[(m0 + sRow) * KH + kb + sCol];
            bReg = *(const short8*)&W1T[(n0 + sRow) * KH + kb + sCol];
        }
        __syncthreads();   // LDS ready
#pragma unroll
        for (int ks2 = 0; ks2 < 2; ++ks2) {
            short8 bf = *(const short8*)&Bs[wcol * 16 + l16][ks2 * 32 + lk8];
            short8 a0 = *(const short8*)&As[wrow * 32 + l16][ks2 * 32 + lk8];
            short8 a1 = *(const short8*)&As[wrow * 32 + 16 + l16][ks2 * 32 + lk8];
            acc0 = __builtin_amdgcn_mfma_f32_16x16x32_bf16(a0, bf, acc0, 0, 0, 0);
            acc1 = __builtin_amdgcn_mfma_f32_16x16x32_bf16(a1, bf, acc1, 0, 0, 0);
        }
    }
    {   // store fp32 partials: D row=(lane>>4)*4+reg, col=lane&15
        float* P = Hp + (size_t)ksp * (B_ * DM);
        int prow = (lane >> 4) * 4;
        int pcol = n0 + wcol * 16 + l16;
#pragma unroll
        for (int r = 0; r < 4; r++) {
            P[(m0 + wrow * 32 + prow + r) * DM + pcol]      = acc0[r];
            P[(m0 + wrow * 32 + 16 + prow + r) * DM + pcol] = acc1[r];
        }
    }
}

// ---------------------------------------------------------------------------
// K2: head + main fused, one block per batch, 1024 threads (16 waves).
// ---------------------------------------------------------------------------
__global__ __launch_bounds__(1024, 1) void k2_head_main(
    const float* __restrict__ ws_ro, const float* __restrict__ b1,
    const float* __restrict__ lg, const float* __restrict__ lb,
    const float* __restrict__ W2, const float* __restrict__ b2,
    const float* __restrict__ phi_prev, const float* __restrict__ x2,
    float* __restrict__ out) {
    __shared__ float2 hred2[16];
    __shared__ float4 hred4[16];
    __shared__ float  cbc[8];
    __shared__ float2 xs[256];
    __shared__ float2 sred[3][256];

    const float2* wT = (const float2*)(ws_ro + WS_WT);
    const float*  Hp = ws_ro + WS_PART;

    int b = blockIdx.x;
    int tid = threadIdx.x;
    int lane = tid & 63, wid = tid >> 6;

    if (tid < 512) ((float*)xs)[tid] = x2[b * (N_ * 2) + tid];

    // ---- head: h = sum_s Hp[s][b][tid] + b1[tid] ----
    float h = b1[tid];
#pragma unroll
    for (int s = 0; s < SPLITS; ++s)
        h += Hp[(size_t)s * (B_ * DM) + b * DM + tid];
    float s1v = h, s2v = h * h;
#pragma unroll
    for (int off = 32; off > 0; off >>= 1) {
        s1v += __shfl_down(s1v, off);
        s2v += __shfl_down(s2v, off);
    }
    if (lane == 0) hred2[wid] = make_float2(s1v, s2v);
    __syncthreads();
    float ms = 0.f, vs = 0.f;
#pragma unroll
    for (int w = 0; w < 16; ++w) { ms += hred2[w].x; vs += hred2[w].y; }
    float mean = ms * (1.f / DM);
    float var  = vs * (1.f / DM) - mean * mean;
    float rstd = rsqrtf(var + 1e-5f);

    float y = fmaxf((h - mean) * rstd * lg[tid] + lb[tid], 0.f);
    float4 w4 = *(const float4*)&W2[tid * 4];
    float4 pv = make_float4(y * w4.x, y * w4.y, y * w4.z, y * w4.w);
#pragma unroll
    for (int off = 32; off > 0; off >>= 1) {
        pv.x += __shfl_down(pv.x, off);
        pv.y += __shfl_down(pv.y, off);
        pv.z += __shfl_down(pv.z, off);
        pv.w += __shfl_down(pv.w, off);
    }
    if (lane == 0) hred4[wid] = pv;
    __syncthreads();
    if (tid == 0) {
        float P0 = b2[0], P1 = b2[1], P2 = b2[2], P3 = b2[3];
#pragma unroll
        for (int w = 0; w < 16; ++w) {
            float4 o = hred4[w];
            P0 += o.x; P1 += o.y; P2 += o.z; P3 += o.w;
        }
        float dphi0 = tanhf(P0) * PI24;
        float dphi1 = tanhf(P2) * PI24;
        float phi0 = phi_prev[b * 2 + 0] + dphi0;
        float phi1 = phi_prev[b * 2 + 1] + dphi1;
        float r0 = 1.f / (1.f + expf(-P1));
        float r1 = 1.f / (1.f + expf(-P3));
        out[B_ * N_ * 2 + b * 2 + 0] = phi0;
        out[B_ * N_ * 2 + b * 2 + 1] = phi1;
        out[B_ * N_ * 2 + B_ * 2 + b * 2 + 0] = dphi0;
        out[B_ * N_ * 2 + B_ * 2 + b * 2 + 1] = dphi1;
        cbc[0] = phi0 - phi1;   // delta
        cbc[1] = r1;
        cbc[2] = r0 - r1;       // dr
        cbc[3] = cosf(phi1);
        cbc[4] = sinf(phi1);
    }
    __syncthreads();
    float delta = cbc[0], r1v = cbc[1], drv = cbc[2], c1 = cbc[3], sn1 = cbc[4];

    // ---- main: i = tid&255, j-quarter = tid>>8 (64 j's each) ----
    int i = tid & 255, jq = tid >> 8;
    int jbase = jq * 64;
    const float2* wp = &wT[jbase * N_ + i];

    float ar0 = 0.f, ai0 = 0.f, ar1 = 0.f, ai1 = 0.f;
#pragma unroll 4
    for (int jj = 0; jj < 64; jj += 2) {
        {
            float2 w = wp[(size_t)jj * N_];
            float r = fmaf(w.x, drv, r1v);
            float g = r * w.y;                       // in (0, 0.4)
            float u = g * g;
            // 1.1*tanh(g) = g*(1.1 + u*(-1.1/3 + u*(2.2/15 - u*1.1*17/315)))
            float tp = fmaf(u, fmaf(u, fmaf(u, -0.059365079f, 0.14666667f),
                                    -0.36666667f), 1.1f);
            float A = g * tp;
            float ang = w.x * delta;
            float sn = __sinf(ang);
            float cs = __cosf(ang);
            float2 xv = xs[jbase + jj];
            float ar = A * cs, as_ = A * sn;
            ar0 = fmaf(ar, xv.x, ar0); ar0 = fmaf(-as_, xv.y, ar0);
            ai0 = fmaf(as_, xv.x, ai0); ai0 = fmaf(ar, xv.y, ai0);
        }
        {
            float2 w = wp[(size_t)(jj + 1) * N_];
            float r = fmaf(w.x, drv, r1v);
            float g = r * w.y;
            float u = g * g;
            float tp = fmaf(u, fmaf(u, fmaf(u, -0.059365079f, 0.14666667f),
                                    -0.36666667f), 1.1f);
            float A = g * tp;
            float ang = w.x * delta;
            float sn = __sinf(ang);
            float cs = __cosf(ang);
            float2 xv = xs[jbase + jj + 1];
            float ar = A * cs, as_ = A * sn;
            ar1 = fmaf(ar, xv.x, ar1); ar1 = fmaf(-as_, xv.y, ar1);
            ai1 = fmaf(as_, xv.x, ai1); ai1 = fmaf(ar, xv.y, ai1);
        }
    }
    float accr = ar0 + ar1, acci = ai0 + ai1;
    if (jq) sred[jq - 1][i] = make_float2(accr, acci);
    __syncthreads();
    if (!jq) {
#pragma unroll
        for (int q = 0; q < 3; ++q) {
            float2 o = sred[q][i];
            accr += o.x; acci += o.y;
        }
        float outr = c1 * accr - sn1 * acci;
        float outi = sn1 * accr + c1 * acci;
        ((float2*)out)[b * N_ + i] = make_float2(outr, outi);
    }
}

// ---------------------------------------------------------------------------
extern "C" void kernel_launch(void* const* d_in, const int* in_sizes, int n_in,
                              void* d_out, int out_size, void* d_ws, size_t ws_size,
                              hipStream_t stream) {
    const float* x_2ch    = (const float*)d_in[0];
    const float* history  = (const float*)d_in[1];
    const float* phi_prev = (const float*)d_in[2];
    const float* S        = (const float*)d_in[3];
    const float* W1       = (const float*)d_in[4];
    const float* b1       = (const float*)d_in[5];
    const float* ln_g     = (const float*)d_in[6];
    const float* ln_b     = (const float*)d_in[7];
    const float* W2       = (const float*)d_in[8];
    const float* b2       = (const float*)d_in[9];
    const float* path_w   = (const float*)d_in[10];

    float* out = (float*)d_out;
    float* ws  = (float*)d_ws;

    k0_convert  <<<464, 512, 0, stream>>>(history, W1, path_w, S, ws);
    k1_gemm     <<<256, 512, 0, stream>>>(ws, ws);
    k2_head_main<<<256, 1024, 0, stream>>>(ws, b1, ln_g, ln_b, W2, b2,
                                           phi_prev, x_2ch, out);
}

// Round 8
// 33.224 us; speedup vs baseline: 1.2451x; 1.0069x over previous
//
#include <hip/hip_runtime.h>
#include <hip/hip_bf16.h>
#include <math.h>

#define N_   256
#define B_   256
#define DM   1024
#define KH   1280   // n*5
#define PI24 0.13089969389957473f
#define SPLITS 4
#define KC    320   // K per split
#define NSUB  5     // KC / 64

// ws layout (floats):
//   wT : [0, 131072)          65536 float2 (w0, relu(S)) transposed [j][i]
//   Hp : [131072, +4*262144)  split-K partials (fp32)
#define WS_WT    0
#define WS_PART  131072

typedef __attribute__((ext_vector_type(8))) short short8;
typedef __attribute__((ext_vector_type(4))) float f32x4;

__device__ inline short f2bf_s(float f) {
    __hip_bfloat16 h = __float2bfloat16(f);   // RNE; compiler fuses pairs to v_cvt_pk_bf16_f32
    return *reinterpret_cast<short*>(&h);
}

// ---------------------------------------------------------------------------
// K1: blocks 0..255: bf16-MFMA GEMM h = hist @ W1 (64x64 tiles, split-K=4),
//     staging converts fp32->bf16 inline (cvt_pk).
//     blocks 256..319: prep  w0 = sigmoid(p0-p1), s = relu(S) -> wT[j][i]
// ---------------------------------------------------------------------------
__global__ __launch_bounds__(512, 4) void k1_gemm_prep(
    const float* __restrict__ hist, const float* __restrict__ W1,
    const float* __restrict__ pw,   const float* __restrict__ S,
    float* __restrict__ ws) {

    __shared__ union {
        struct {
            unsigned short As[64][72];   // [m][k] bf16, stride 72
            unsigned short Bs[64][72];   // [n][k] bf16
        } g;
        float2 ptile[32][33];
    } sh;

    float2* wT = (float2*)(ws + WS_WT);
    float*  Hp = ws + WS_PART;

    int bid = blockIdx.x, tid = threadIdx.x;

    // ================= prep blocks =================
    if (bid >= 256) {
        int pb = bid - 256;
        int i0 = (pb >> 3) * 32, j0 = (pb & 7) * 32;
#pragma unroll
        for (int rep = 0; rep < 2; ++rep) {
            int idx = rep * 512 + tid;
            int r = idx >> 5, c = idx & 31;          // r: local i, c: local j
            float2 p = *(const float2*)&pw[((i0 + r) * N_ + j0 + c) * 2];
            float sv = S[(i0 + r) * N_ + j0 + c];
            float w0 = 1.f / (1.f + __expf(p.y - p.x));
            sh.ptile[r][c] = make_float2(w0, fmaxf(sv, 0.f));
        }
        __syncthreads();
#pragma unroll
        for (int rep = 0; rep < 2; ++rep) {
            int idx = rep * 512 + tid;
            int r = idx >> 5, c = idx & 31;          // r: local j, c: local i
            wT[(j0 + r) * N_ + i0 + c] = sh.ptile[c][r];
        }
        return;
    }

    // ================= GEMM blocks =================
    int t64 = bid & 63, ksp = bid >> 6;
    int m0 = (t64 >> 4) * 64, n0 = (t64 & 15) * 64;
    int kbase = ksp * KC;

    int lane = tid & 63, wv = tid >> 6;
    int wrow = wv & 1, wcol = wv >> 1;
    int l16 = lane & 15, lk8 = (lane >> 4) * 8;
    int aRow = tid >> 3, aCol = (tid & 7) * 8;    // A stage: 64 rows x 64 k
    int bN = tid & 63, bK0 = wv * 8;              // B stage: 8 k for one n

    float4 aV0, aV1; float bV[8];
    {
        const float* ap = &hist[(m0 + aRow) * KH + kbase + aCol];
        aV0 = *(const float4*)ap;
        aV1 = *(const float4*)(ap + 4);
#pragma unroll
        for (int i = 0; i < 8; i++)
            bV[i] = W1[(kbase + bK0 + i) * DM + n0 + bN];
    }

    f32x4 acc0 = {0.f, 0.f, 0.f, 0.f};
    f32x4 acc1 = {0.f, 0.f, 0.f, 0.f};

    for (int s = 0; s < NSUB; ++s) {
        __syncthreads();
        {
            float av[8] = {aV0.x, aV0.y, aV0.z, aV0.w, aV1.x, aV1.y, aV1.z, aV1.w};
            short8 va, vb;
#pragma unroll
            for (int i = 0; i < 8; i++) { va[i] = f2bf_s(av[i]); vb[i] = f2bf_s(bV[i]); }
            *(short8*)&sh.g.As[aRow][aCol] = va;
            *(short8*)&sh.g.Bs[bN][bK0] = vb;
        }
        if (s + 1 < NSUB) {
            int kb = kbase + (s + 1) * 64;
            const float* ap = &hist[(m0 + aRow) * KH + kb + aCol];
            aV0 = *(const float4*)ap;
            aV1 = *(const float4*)(ap + 4);
#pragma unroll
            for (int i = 0; i < 8; i++)
                bV[i] = W1[(kb + bK0 + i) * DM + n0 + bN];
        }
        __syncthreads();
#pragma unroll
        for (int ks2 = 0; ks2 < 2; ++ks2) {
            short8 bf = *(const short8*)&sh.g.Bs[wcol * 16 + l16][ks2 * 32 + lk8];
            short8 a0 = *(const short8*)&sh.g.As[wrow * 32 + l16][ks2 * 32 + lk8];
            short8 a1 = *(const short8*)&sh.g.As[wrow * 32 + 16 + l16][ks2 * 32 + lk8];
            acc0 = __builtin_amdgcn_mfma_f32_16x16x32_bf16(a0, bf, acc0, 0, 0, 0);
            acc1 = __builtin_amdgcn_mfma_f32_16x16x32_bf16(a1, bf, acc1, 0, 0, 0);
        }
    }
    {   // store fp32 partials: D row=(lane>>4)*4+reg, col=lane&15
        float* P = Hp + (size_t)ksp * (B_ * DM);
        int prow = (lane >> 4) * 4;
        int pcol = n0 + wcol * 16 + l16;
#pragma unroll
        for (int r = 0; r < 4; r++) {
            P[(m0 + wrow * 32 + prow + r) * DM + pcol]      = acc0[r];
            P[(m0 + wrow * 32 + 16 + prow + r) * DM + pcol] = acc1[r];
        }
    }
}

// ---------------------------------------------------------------------------
// K2: head + main for a PAIR of batches, j-half per block.
// grid 256 = (128 batch-pairs) x (2 j-halves); 1024 threads.
// Head: 512 threads per batch (t=tid&511, bh=tid>>9), 2 h-els each.
// Main: i=tid&255, jq=tid>>8 (4 x 32 j of this block's 128-j window);
//       each thread loads (w0,s) ONCE and computes BOTH batches.
// ---------------------------------------------------------------------------
__global__ __launch_bounds__(1024, 1) void k2_head_main(
    const float* __restrict__ ws_ro, const float* __restrict__ b1,
    const float* __restrict__ lg, const float* __restrict__ lb,
    const float* __restrict__ W2, const float* __restrict__ b2,
    const float* __restrict__ phi_prev, const float* __restrict__ x2,
    float* __restrict__ out) {
    __shared__ float2 hred2[16];
    __shared__ float4 hred4[16];
    __shared__ float  cbc[2][8];
    __shared__ float2 xs[2][128];
    __shared__ float4 sred[3][256];

    const float2* wT = (const float2*)(ws_ro + WS_WT);
    const float*  Hp = ws_ro + WS_PART;

    int bid = blockIdx.x, tid = threadIdx.x;
    int b0 = (bid >> 1) * 2;          // batch pair base
    int jhb = bid & 1;                // j-half: 0 -> j 0..127, 1 -> j 128..255
    int lane = tid & 63, wid = tid >> 6;
    int t = tid & 511, bh = tid >> 9; // head: batch half
    int b = b0 + bh;

    // x slice for this block's j-window, both batches
    if (tid < 512) {
        int bx = tid >> 8, jj = tid & 255;
        ((float*)&xs[bx][0])[jj] = x2[(b0 + bx) * (N_ * 2) + jhb * 256 + jj];
    }

    // ---- head (per batch half): h = sum_s Hp[s][b] + b1 ----
    float2 b12 = *(const float2*)&b1[t * 2];
    float h0 = b12.x, h1 = b12.y;
#pragma unroll
    for (int s = 0; s < SPLITS; ++s) {
        float2 p = *(const float2*)&Hp[(size_t)s * (B_ * DM) + b * DM + t * 2];
        h0 += p.x; h1 += p.y;
    }
    float s1v = h0 + h1, s2v = h0 * h0 + h1 * h1;
#pragma unroll
    for (int off = 32; off > 0; off >>= 1) {
        s1v += __shfl_down(s1v, off);
        s2v += __shfl_down(s2v, off);
    }
    if (lane == 0) hred2[wid] = make_float2(s1v, s2v);
    __syncthreads();
    float ms = 0.f, vs = 0.f;
#pragma unroll
    for (int w = 0; w < 8; ++w) { ms += hred2[bh * 8 + w].x; vs += hred2[bh * 8 + w].y; }
    float mean = ms * (1.f / DM);
    float var  = vs * (1.f / DM) - mean * mean;
    float rstd = rsqrtf(var + 1e-5f);

    float2 g2  = *(const float2*)&lg[t * 2];
    float2 be2 = *(const float2*)&lb[t * 2];
    float y0 = fmaxf((h0 - mean) * rstd * g2.x + be2.x, 0.f);
    float y1 = fmaxf((h1 - mean) * rstd * g2.y + be2.y, 0.f);
    float4 wA = *(const float4*)&W2[(t * 2) * 4];
    float4 wB = *(const float4*)&W2[(t * 2 + 1) * 4];
    float4 pv;
    pv.x = y0 * wA.x + y1 * wB.x;
    pv.y = y0 * wA.y + y1 * wB.y;
    pv.z = y0 * wA.z + y1 * wB.z;
    pv.w = y0 * wA.w + y1 * wB.w;
#pragma unroll
    for (int off = 32; off > 0; off >>= 1) {
        pv.x += __shfl_down(pv.x, off);
        pv.y += __shfl_down(pv.y, off);
        pv.z += __shfl_down(pv.z, off);
        pv.w += __shfl_down(pv.w, off);
    }
    if (lane == 0) hred4[wid] = pv;
    __syncthreads();
    if (t == 0) {   // tid==0 (batch0) and tid==512 (batch1)
        float P0 = b2[0], P1 = b2[1], P2 = b2[2], P3 = b2[3];
#pragma unroll
        for (int w = 0; w < 8; ++w) {
            float4 o = hred4[bh * 8 + w];
            P0 += o.x; P1 += o.y; P2 += o.z; P3 += o.w;
        }
        float dphi0 = tanhf(P0) * PI24;
        float dphi1 = tanhf(P2) * PI24;
        float phi0 = phi_prev[b * 2 + 0] + dphi0;
        float phi1 = phi_prev[b * 2 + 1] + dphi1;
        float r0 = 1.f / (1.f + expf(-P1));
        float r1 = 1.f / (1.f + expf(-P3));
        out[B_ * N_ * 2 + b * 2 + 0] = phi0;
        out[B_ * N_ * 2 + b * 2 + 1] = phi1;
        out[B_ * N_ * 2 + B_ * 2 + b * 2 + 0] = dphi0;
        out[B_ * N_ * 2 + B_ * 2 + b * 2 + 1] = dphi1;
        cbc[bh][0] = phi0 - phi1;   // delta
        cbc[bh][1] = r1;
        cbc[bh][2] = r0 - r1;       // dr
        cbc[bh][3] = cosf(phi1);
        cbc[bh][4] = sinf(phi1);
    }
    __syncthreads();
    float dl0 = cbc[0][0], r10 = cbc[0][1], dr0 = cbc[0][2];
    float dl1 = cbc[1][0], r11 = cbc[1][1], dr1 = cbc[1][2];

    // ---- main: 32 j per thread, both batches per (w0,s) load ----
    int i = tid & 255, jq = tid >> 8;
    int jloc = jq * 32;
    const float2* wp = &wT[(jhb * 128 + jloc) * N_ + i];

    float ar0 = 0.f, ai0 = 0.f, ar1 = 0.f, ai1 = 0.f;
#pragma unroll 4
    for (int jj = 0; jj < 32; ++jj) {
        float2 w = wp[(size_t)jj * N_];
        float u_base;
        // shared: g-poly pieces per batch (r differs by batch)
        float2 xv0 = xs[0][jloc + jj];
        float2 xv1 = xs[1][jloc + jj];
        {   // batch 0
            float r = fmaf(w.x, dr0, r10);
            float g = r * w.y;                       // in (0, 0.4)
            float u = g * g;
            float tp = fmaf(u, fmaf(u, fmaf(u, -0.059365079f, 0.14666667f),
                                    -0.36666667f), 1.1f);
            float A = g * tp;
            float ang = w.x * dl0;
            float sn = __sinf(ang);
            float cs = __cosf(ang);
            float ar = A * cs, as_ = A * sn;
            ar0 = fmaf(ar, xv0.x, ar0); ar0 = fmaf(-as_, xv0.y, ar0);
            ai0 = fmaf(as_, xv0.x, ai0); ai0 = fmaf(ar, xv0.y, ai0);
        }
        {   // batch 1
            float r = fmaf(w.x, dr1, r11);
            float g = r * w.y;
            float u = g * g;
            float tp = fmaf(u, fmaf(u, fmaf(u, -0.059365079f, 0.14666667f),
                                    -0.36666667f), 1.1f);
            float A = g * tp;
            float ang = w.x * dl1;
            float sn = __sinf(ang);
            float cs = __cosf(ang);
            float ar = A * cs, as_ = A * sn;
            ar1 = fmaf(ar, xv1.x, ar1); ar1 = fmaf(-as_, xv1.y, ar1);
            ai1 = fmaf(as_, xv1.x, ai1); ai1 = fmaf(ar, xv1.y, ai1);
        }
        (void)u_base;
    }
    if (jq) sred[jq - 1][i] = make_float4(ar0, ai0, ar1, ai1);
    __syncthreads();
    if (!jq) {
#pragma unroll
        for (int q = 0; q < 3; ++q) {
            float4 o = sred[q][i];
            ar0 += o.x; ai0 += o.y; ar1 += o.z; ai1 += o.w;
        }
        // rotate by e^{i phi1} per batch and atomically-free accumulate:
        // two blocks (jhb 0/1) each hold a partial sum over their j-half.
        // Combine via direct store? Both halves needed -> use atomicAdd-free
        // split: each jhb writes its own half to out via atomicAdd.
        float c10 = cbc[0][3], s10 = cbc[0][4];
        float c11 = cbc[1][3], s11 = cbc[1][4];
        float o0r = c10 * ar0 - s10 * ai0;
        float o0i = s10 * ar0 + c10 * ai0;
        float o1r = c11 * ar1 - s11 * ai1;
        float o1i = s11 * ar1 + c11 * ai1;
        atomicAdd(&out[(b0 * N_ + i) * 2],     o0r);
        atomicAdd(&out[(b0 * N_ + i) * 2 + 1], o0i);
        atomicAdd(&out[((b0 + 1) * N_ + i) * 2],     o1r);
        atomicAdd(&out[((b0 + 1) * N_ + i) * 2 + 1], o1i);
    }
}

// ---------------------------------------------------------------------------
// K2 needs out[0 : B*N*2) zeroed for its atomicAdd j-half combine.
// Zero it inside K1's prep blocks? No - K1 runs concurrently with nothing
// else; prep blocks can zero it (out region is only written by K2).
// ---------------------------------------------------------------------------

extern "C" void kernel_launch(void* const* d_in, const int* in_sizes, int n_in,
                              void* d_out, int out_size, void* d_ws, size_t ws_size,
                              hipStream_t stream) {
    const float* x_2ch    = (const float*)d_in[0];
    const float* history  = (const float*)d_in[1];
    const float* phi_prev = (const float*)d_in[2];
    const float* S        = (const float*)d_in[3];
    const float* W1       = (const float*)d_in[4];
    const float* b1       = (const float*)d_in[5];
    const float* ln_g     = (const float*)d_in[6];
    const float* ln_b     = (const float*)d_in[7];
    const float* W2       = (const float*)d_in[8];
    const float* b2       = (const float*)d_in[9];
    const float* path_w   = (const float*)d_in[10];

    float* out = (float*)d_out;
    float* ws  = (float*)d_ws;

    // zero the next_x region of out for K2's 2-block j-half atomic combine
    hipMemsetAsync(out, 0, (size_t)B_ * N_ * 2 * sizeof(float), stream);

    k1_gemm_prep<<<320, 512, 0, stream>>>(history, W1, path_w, S, ws);
    k2_head_main<<<256, 1024, 0, stream>>>(ws, b1, ln_g, ln_b, W2, b2,
                                           phi_prev, x_2ch, out);
}

// Round 9
// 27.670 us; speedup vs baseline: 1.4951x; 1.2007x over previous
//
#include <hip/hip_runtime.h>
#include <hip/hip_bf16.h>
#include <math.h>

#define N_   256
#define B_   256
#define DM   1024
#define KH   1280   // n*5
#define PI24 0.13089969389957473f
#define SPLITS 4
#define KC    320   // K per split
#define NSUB  5     // KC / 64

// ws layout (floats):
//   wT : [0, 131072)          65536 float2 (w0, relu(S)) transposed [j][i]
//   Hp : [131072, +4*262144)  split-K partials (fp32)
#define WS_WT    0
#define WS_PART  131072

typedef __attribute__((ext_vector_type(8))) short short8;
typedef __attribute__((ext_vector_type(4))) float f32x4;

__device__ inline short f2bf_s(float f) {
    __hip_bfloat16 h = __float2bfloat16(f);   // RNE; pairs fuse to v_cvt_pk_bf16_f32
    return *reinterpret_cast<short*>(&h);
}

// ---------------------------------------------------------------------------
// K1: blocks 0..255: bf16-MFMA GEMM h = hist @ W1 (64x64 tiles, split-K=4),
//     staging converts fp32->bf16 inline (cvt_pk).
//     blocks 256..319: prep (w0 = sigmoid(p0-p1), s = relu(S) -> wT[j][i])
//                      + zero out[0:B*N*2] for K2's atomic j-half combine.
// ---------------------------------------------------------------------------
__global__ __launch_bounds__(512, 4) void k1_gemm_prep(
    const float* __restrict__ hist, const float* __restrict__ W1,
    const float* __restrict__ pw,   const float* __restrict__ S,
    float* __restrict__ ws, float* __restrict__ out) {

    __shared__ union {
        struct {
            unsigned short As[64][72];   // [m][k] bf16, stride 72
            unsigned short Bs[64][72];   // [n][k] bf16
        } g;
        float2 ptile[32][33];
    } sh;

    float2* wT = (float2*)(ws + WS_WT);
    float*  Hp = ws + WS_PART;

    int bid = blockIdx.x, tid = threadIdx.x;

    // ================= prep + out-zero blocks =================
    if (bid >= 256) {
        int pb = bid - 256;
        // zero this block's slice of out[0 : 131072) (2048 floats/block)
        *(float4*)&out[pb * 2048 + tid * 4] =
            make_float4(0.f, 0.f, 0.f, 0.f);

        int i0 = (pb >> 3) * 32, j0 = (pb & 7) * 32;
#pragma unroll
        for (int rep = 0; rep < 2; ++rep) {
            int idx = rep * 512 + tid;
            int r = idx >> 5, c = idx & 31;          // r: local i, c: local j
            float2 p = *(const float2*)&pw[((i0 + r) * N_ + j0 + c) * 2];
            float sv = S[(i0 + r) * N_ + j0 + c];
            float w0 = 1.f / (1.f + __expf(p.y - p.x));
            sh.ptile[r][c] = make_float2(w0, fmaxf(sv, 0.f));
        }
        __syncthreads();
#pragma unroll
        for (int rep = 0; rep < 2; ++rep) {
            int idx = rep * 512 + tid;
            int r = idx >> 5, c = idx & 31;          // r: local j, c: local i
            wT[(j0 + r) * N_ + i0 + c] = sh.ptile[c][r];
        }
        return;
    }

    // ================= GEMM blocks =================
    int t64 = bid & 63, ksp = bid >> 6;
    int m0 = (t64 >> 4) * 64, n0 = (t64 & 15) * 64;
    int kbase = ksp * KC;

    int lane = tid & 63, wv = tid >> 6;
    int wrow = wv & 1, wcol = wv >> 1;
    int l16 = lane & 15, lk8 = (lane >> 4) * 8;
    int aRow = tid >> 3, aCol = (tid & 7) * 8;    // A stage: 64 rows x 64 k
    int bN = tid & 63, bK0 = wv * 8;              // B stage: 8 k for one n

    float4 aV0, aV1; float bV[8];
    {
        const float* ap = &hist[(m0 + aRow) * KH + kbase + aCol];
        aV0 = *(const float4*)ap;
        aV1 = *(const float4*)(ap + 4);
#pragma unroll
        for (int i = 0; i < 8; i++)
            bV[i] = W1[(kbase + bK0 + i) * DM + n0 + bN];
    }

    f32x4 acc0 = {0.f, 0.f, 0.f, 0.f};
    f32x4 acc1 = {0.f, 0.f, 0.f, 0.f};

    for (int s = 0; s < NSUB; ++s) {
        __syncthreads();
        {
            float av[8] = {aV0.x, aV0.y, aV0.z, aV0.w, aV1.x, aV1.y, aV1.z, aV1.w};
            short8 va, vb;
#pragma unroll
            for (int i = 0; i < 8; i++) { va[i] = f2bf_s(av[i]); vb[i] = f2bf_s(bV[i]); }
            *(short8*)&sh.g.As[aRow][aCol] = va;
            *(short8*)&sh.g.Bs[bN][bK0] = vb;
        }
        if (s + 1 < NSUB) {
            int kb = kbase + (s + 1) * 64;
            const float* ap = &hist[(m0 + aRow) * KH + kb + aCol];
            aV0 = *(const float4*)ap;
            aV1 = *(const float4*)(ap + 4);
#pragma unroll
            for (int i = 0; i < 8; i++)
                bV[i] = W1[(kb + bK0 + i) * DM + n0 + bN];
        }
        __syncthreads();
#pragma unroll
        for (int ks2 = 0; ks2 < 2; ++ks2) {
            short8 bf = *(const short8*)&sh.g.Bs[wcol * 16 + l16][ks2 * 32 + lk8];
            short8 a0 = *(const short8*)&sh.g.As[wrow * 32 + l16][ks2 * 32 + lk8];
            short8 a1 = *(const short8*)&sh.g.As[wrow * 32 + 16 + l16][ks2 * 32 + lk8];
            acc0 = __builtin_amdgcn_mfma_f32_16x16x32_bf16(a0, bf, acc0, 0, 0, 0);
            acc1 = __builtin_amdgcn_mfma_f32_16x16x32_bf16(a1, bf, acc1, 0, 0, 0);
        }
    }
    {   // store fp32 partials: D row=(lane>>4)*4+reg, col=lane&15
        float* P = Hp + (size_t)ksp * (B_ * DM);
        int prow = (lane >> 4) * 4;
        int pcol = n0 + wcol * 16 + l16;
#pragma unroll
        for (int r = 0; r < 4; r++) {
            P[(m0 + wrow * 32 + prow + r) * DM + pcol]      = acc0[r];
            P[(m0 + wrow * 32 + 16 + prow + r) * DM + pcol] = acc1[r];
        }
    }
}

// ---------------------------------------------------------------------------
// K2: head + main for a PAIR of batches, j-half per block.
// grid 256 = (128 batch-pairs) x (2 j-halves); 1024 threads.
// ---------------------------------------------------------------------------
__global__ __launch_bounds__(1024, 1) void k2_head_main(
    const float* __restrict__ ws_ro, const float* __restrict__ b1,
    const float* __restrict__ lg, const float* __restrict__ lb,
    const float* __restrict__ W2, const float* __restrict__ b2,
    const float* __restrict__ phi_prev, const float* __restrict__ x2,
    float* __restrict__ out) {
    __shared__ float2 hred2[16];
    __shared__ float4 hred4[16];
    __shared__ float  cbc[2][8];
    __shared__ float2 xs[2][128];
    __shared__ float4 sred[3][256];

    const float2* wT = (const float2*)(ws_ro + WS_WT);
    const float*  Hp = ws_ro + WS_PART;

    int bid = blockIdx.x, tid = threadIdx.x;
    int b0 = (bid >> 1) * 2;          // batch pair base
    int jhb = bid & 1;                // j-half: 0 -> j 0..127, 1 -> j 128..255
    int lane = tid & 63, wid = tid >> 6;
    int t = tid & 511, bh = tid >> 9; // head: batch half
    int b = b0 + bh;

    if (tid < 512) {
        int bx = tid >> 8, jj = tid & 255;
        ((float*)&xs[bx][0])[jj] = x2[(b0 + bx) * (N_ * 2) + jhb * 256 + jj];
    }

    // ---- head (per batch half): h = sum_s Hp[s][b] + b1 ----
    float2 b12 = *(const float2*)&b1[t * 2];
    float h0 = b12.x, h1 = b12.y;
#pragma unroll
    for (int s = 0; s < SPLITS; ++s) {
        float2 p = *(const float2*)&Hp[(size_t)s * (B_ * DM) + b * DM + t * 2];
        h0 += p.x; h1 += p.y;
    }
    float s1v = h0 + h1, s2v = h0 * h0 + h1 * h1;
#pragma unroll
    for (int off = 32; off > 0; off >>= 1) {
        s1v += __shfl_down(s1v, off);
        s2v += __shfl_down(s2v, off);
    }
    if (lane == 0) hred2[wid] = make_float2(s1v, s2v);
    __syncthreads();
    float ms = 0.f, vs = 0.f;
#pragma unroll
    for (int w = 0; w < 8; ++w) { ms += hred2[bh * 8 + w].x; vs += hred2[bh * 8 + w].y; }
    float mean = ms * (1.f / DM);
    float var  = vs * (1.f / DM) - mean * mean;
    float rstd = rsqrtf(var + 1e-5f);

    float2 g2  = *(const float2*)&lg[t * 2];
    float2 be2 = *(const float2*)&lb[t * 2];
    float y0 = fmaxf((h0 - mean) * rstd * g2.x + be2.x, 0.f);
    float y1 = fmaxf((h1 - mean) * rstd * g2.y + be2.y, 0.f);
    float4 wA = *(const float4*)&W2[(t * 2) * 4];
    float4 wB = *(const float4*)&W2[(t * 2 + 1) * 4];
    float4 pv;
    pv.x = y0 * wA.x + y1 * wB.x;
    pv.y = y0 * wA.y + y1 * wB.y;
    pv.z = y0 * wA.z + y1 * wB.z;
    pv.w = y0 * wA.w + y1 * wB.w;
#pragma unroll
    for (int off = 32; off > 0; off >>= 1) {
        pv.x += __shfl_down(pv.x, off);
        pv.y += __shfl_down(pv.y, off);
        pv.z += __shfl_down(pv.z, off);
        pv.w += __shfl_down(pv.w, off);
    }
    if (lane == 0) hred4[wid] = pv;
    __syncthreads();
    if (t == 0) {   // tid==0 (batch0) and tid==512 (batch1)
        float P0 = b2[0], P1 = b2[1], P2 = b2[2], P3 = b2[3];
#pragma unroll
        for (int w = 0; w < 8; ++w) {
            float4 o = hred4[bh * 8 + w];
            P0 += o.x; P1 += o.y; P2 += o.z; P3 += o.w;
        }
        float dphi0 = tanhf(P0) * PI24;
        float dphi1 = tanhf(P2) * PI24;
        float phi0 = phi_prev[b * 2 + 0] + dphi0;
        float phi1 = phi_prev[b * 2 + 1] + dphi1;
        float r0 = 1.f / (1.f + expf(-P1));
        float r1 = 1.f / (1.f + expf(-P3));
        out[B_ * N_ * 2 + b * 2 + 0] = phi0;
        out[B_ * N_ * 2 + b * 2 + 1] = phi1;
        out[B_ * N_ * 2 + B_ * 2 + b * 2 + 0] = dphi0;
        out[B_ * N_ * 2 + B_ * 2 + b * 2 + 1] = dphi1;
        cbc[bh][0] = phi0 - phi1;   // delta
        cbc[bh][1] = r1;
        cbc[bh][2] = r0 - r1;       // dr
        cbc[bh][3] = cosf(phi1);
        cbc[bh][4] = sinf(phi1);
    }
    __syncthreads();
    float dl0 = cbc[0][0], r10 = cbc[0][1], dr0 = cbc[0][2];
    float dl1 = cbc[1][0], r11 = cbc[1][1], dr1 = cbc[1][2];

    // ---- main: 32 j per thread, both batches per (w0,s) load ----
    int i = tid & 255, jq = tid >> 8;
    int jloc = jq * 32;
    const float2* wp = &wT[(jhb * 128 + jloc) * N_ + i];

    float ar0 = 0.f, ai0 = 0.f, ar1 = 0.f, ai1 = 0.f;
#pragma unroll 4
    for (int jj = 0; jj < 32; ++jj) {
        float2 w = wp[(size_t)jj * N_];
        float2 xv0 = xs[0][jloc + jj];
        float2 xv1 = xs[1][jloc + jj];
        {   // batch 0
            float r = fmaf(w.x, dr0, r10);
            float g = r * w.y;                       // in (0, 0.4)
            float u = g * g;
            // 1.1*tanh(g) ~= g*(1.1 + u*(-1.1/3 + u*2.2/15)), |err|<1e-4
            float tp = fmaf(u, fmaf(u, 0.14666667f, -0.36666667f), 1.1f);
            float A = g * tp;
            float ang = w.x * dl0;
            float sn = __sinf(ang);
            float cs = __cosf(ang);
            float ar = A * cs, as_ = A * sn;
            ar0 = fmaf(ar, xv0.x, ar0); ar0 = fmaf(-as_, xv0.y, ar0);
            ai0 = fmaf(as_, xv0.x, ai0); ai0 = fmaf(ar, xv0.y, ai0);
        }
        {   // batch 1
            float r = fmaf(w.x, dr1, r11);
            float g = r * w.y;
            float u = g * g;
            float tp = fmaf(u, fmaf(u, 0.14666667f, -0.36666667f), 1.1f);
            float A = g * tp;
            float ang = w.x * dl1;
            float sn = __sinf(ang);
            float cs = __cosf(ang);
            float ar = A * cs, as_ = A * sn;
            ar1 = fmaf(ar, xv1.x, ar1); ar1 = fmaf(-as_, xv1.y, ar1);
            ai1 = fmaf(as_, xv1.x, ai1); ai1 = fmaf(ar, xv1.y, ai1);
        }
    }
    if (jq) sred[jq - 1][i] = make_float4(ar0, ai0, ar1, ai1);
    __syncthreads();
    if (!jq) {
#pragma unroll
        for (int q = 0; q < 3; ++q) {
            float4 o = sred[q][i];
            ar0 += o.x; ai0 += o.y; ar1 += o.z; ai1 += o.w;
        }
        float c10 = cbc[0][3], s10 = cbc[0][4];
        float c11 = cbc[1][3], s11 = cbc[1][4];
        float o0r = c10 * ar0 - s10 * ai0;
        float o0i = s10 * ar0 + c10 * ai0;
        float o1r = c11 * ar1 - s11 * ai1;
        float o1i = s11 * ar1 + c11 * ai1;
        atomicAdd(&out[(b0 * N_ + i) * 2],     o0r);
        atomicAdd(&out[(b0 * N_ + i) * 2 + 1], o0i);
        atomicAdd(&out[((b0 + 1) * N_ + i) * 2],     o1r);
        atomicAdd(&out[((b0 + 1) * N_ + i) * 2 + 1], o1i);
    }
}

// ---------------------------------------------------------------------------
extern "C" void kernel_launch(void* const* d_in, const int* in_sizes, int n_in,
                              void* d_out, int out_size, void* d_ws, size_t ws_size,
                              hipStream_t stream) {
    const float* x_2ch    = (const float*)d_in[0];
    const float* history  = (const float*)d_in[1];
    const float* phi_prev = (const float*)d_in[2];
    const float* S        = (const float*)d_in[3];
    const float* W1       = (const float*)d_in[4];
    const float* b1       = (const float*)d_in[5];
    const float* ln_g     = (const float*)d_in[6];
    const float* ln_b     = (const float*)d_in[7];
    const float* W2       = (const float*)d_in[8];
    const float* b2       = (const float*)d_in[9];
    const float* path_w   = (const float*)d_in[10];

    float* out = (float*)d_out;
    float* ws  = (float*)d_ws;

    k1_gemm_prep<<<320, 512, 0, stream>>>(history, W1, path_w, S, ws, out);
    k2_head_main<<<256, 1024, 0, stream>>>(ws, b1, ln_g, ln_b, W2, b2,
                                           phi_prev, x_2ch, out);
}

// Round 10
// 26.013 us; speedup vs baseline: 1.5903x; 1.0637x over previous
//
#include <hip/hip_runtime.h>
#include <hip/hip_bf16.h>
#include <math.h>

#define N_   256
#define B_   256
#define DM   1024
#define KH   1280   // n*5
#define PI24 0.13089969389957473f
#define SPLITS 4
#define KC    320   // K per split
#define NSUB  5     // KC / 64

// ws layout (floats):
//   wT : [0, 131072)          65536 float2 (w0, relu(S)) transposed [j][i]
//   Hp : [131072, +4*262144)  split-K partials (fp32)
#define WS_WT    0
#define WS_PART  131072

typedef __attribute__((ext_vector_type(8))) short short8;
typedef __attribute__((ext_vector_type(4))) float f32x4;

__device__ inline short f2bf_s(float f) {
    __hip_bfloat16 h = __float2bfloat16(f);   // RNE; pairs fuse to v_cvt_pk_bf16_f32
    return *reinterpret_cast<short*>(&h);
}

// ---------------------------------------------------------------------------
// K1: 256 blocks. Each block: (1) register-only prep of one 16x16 (i,j) tile
// of wT + zero 512 floats of out (hidden under initial GEMM load latency),
// (2) bf16-MFMA GEMM h = hist @ W1 (64x64 tile, split-K=4).
// ---------------------------------------------------------------------------
__global__ __launch_bounds__(512, 4) void k1_gemm_prep(
    const float* __restrict__ hist, const float* __restrict__ W1,
    const float* __restrict__ pw,   const float* __restrict__ S,
    float* __restrict__ ws, float* __restrict__ out) {

    __shared__ unsigned short As[64][72];   // [m][k] bf16, stride 72
    __shared__ unsigned short Bs[64][72];   // [n][k] bf16

    float2* wT = (float2*)(ws + WS_WT);
    float*  Hp = ws + WS_PART;

    int bid = blockIdx.x, tid = threadIdx.x;

    // ---- distributed prep: 16x16 tile of (i,j) per block, register-only ----
    if (tid < 256) {
        int i0 = (bid >> 4) * 16, j0 = (bid & 15) * 16;
        int r = tid >> 4, c = tid & 15;
        float2 p = *(const float2*)&pw[((i0 + r) * N_ + j0 + c) * 2];
        float sv = S[(i0 + r) * N_ + j0 + c];
        float w0 = 1.f / (1.f + __expf(p.y - p.x));
        wT[(j0 + c) * N_ + i0 + r] = make_float2(w0, fmaxf(sv, 0.f));
    } else {
        // zero this block's slice of out[0 : 131072) (512 floats/block)
        int t = tid - 256;
        *(float2*)&out[bid * 512 + t * 2] = make_float2(0.f, 0.f);
    }

    // ---- GEMM: 64 tiles (4Mx16N of 64x64) x 4 K-splits ----
    int t64 = bid & 63, ksp = bid >> 6;
    int m0 = (t64 >> 4) * 64, n0 = (t64 & 15) * 64;
    int kbase = ksp * KC;

    int lane = tid & 63, wv = tid >> 6;
    int wrow = wv & 1, wcol = wv >> 1;
    int l16 = lane & 15, lk8 = (lane >> 4) * 8;
    int aRow = tid >> 3, aCol = (tid & 7) * 8;    // A stage: 64 rows x 64 k
    int bN = tid & 63, bK0 = wv * 8;              // B stage: 8 k for one n

    float4 aV0, aV1; float bV[8];
    {
        const float* ap = &hist[(m0 + aRow) * KH + kbase + aCol];
        aV0 = *(const float4*)ap;
        aV1 = *(const float4*)(ap + 4);
#pragma unroll
        for (int i = 0; i < 8; i++)
            bV[i] = W1[(kbase + bK0 + i) * DM + n0 + bN];
    }

    f32x4 acc0 = {0.f, 0.f, 0.f, 0.f};
    f32x4 acc1 = {0.f, 0.f, 0.f, 0.f};

    for (int s = 0; s < NSUB; ++s) {
        __syncthreads();
        {
            float av[8] = {aV0.x, aV0.y, aV0.z, aV0.w, aV1.x, aV1.y, aV1.z, aV1.w};
            short8 va, vb;
#pragma unroll
            for (int i = 0; i < 8; i++) { va[i] = f2bf_s(av[i]); vb[i] = f2bf_s(bV[i]); }
            *(short8*)&As[aRow][aCol] = va;
            *(short8*)&Bs[bN][bK0] = vb;
        }
        if (s + 1 < NSUB) {
            int kb = kbase + (s + 1) * 64;
            const float* ap = &hist[(m0 + aRow) * KH + kb + aCol];
            aV0 = *(const float4*)ap;
            aV1 = *(const float4*)(ap + 4);
#pragma unroll
            for (int i = 0; i < 8; i++)
                bV[i] = W1[(kb + bK0 + i) * DM + n0 + bN];
        }
        __syncthreads();
#pragma unroll
        for (int ks2 = 0; ks2 < 2; ++ks2) {
            short8 bf = *(const short8*)&Bs[wcol * 16 + l16][ks2 * 32 + lk8];
            short8 a0 = *(const short8*)&As[wrow * 32 + l16][ks2 * 32 + lk8];
            short8 a1 = *(const short8*)&As[wrow * 32 + 16 + l16][ks2 * 32 + lk8];
            acc0 = __builtin_amdgcn_mfma_f32_16x16x32_bf16(a0, bf, acc0, 0, 0, 0);
            acc1 = __builtin_amdgcn_mfma_f32_16x16x32_bf16(a1, bf, acc1, 0, 0, 0);
        }
    }
    {   // store fp32 partials: D row=(lane>>4)*4+reg, col=lane&15
        float* P = Hp + (size_t)ksp * (B_ * DM);
        int prow = (lane >> 4) * 4;
        int pcol = n0 + wcol * 16 + l16;
#pragma unroll
        for (int r = 0; r < 4; r++) {
            P[(m0 + wrow * 32 + prow + r) * DM + pcol]      = acc0[r];
            P[(m0 + wrow * 32 + 16 + prow + r) * DM + pcol] = acc1[r];
        }
    }
}

// ---------------------------------------------------------------------------
// K2: head + main, ONE batch per block, j-half per block.
// grid 512 = 256 batches x 2 j-halves; 512 threads (8 waves, 2 blocks/CU).
// ---------------------------------------------------------------------------
__global__ __launch_bounds__(512, 4) void k2_head_main(
    const float* __restrict__ ws_ro, const float* __restrict__ b1,
    const float* __restrict__ lg, const float* __restrict__ lb,
    const float* __restrict__ W2, const float* __restrict__ b2,
    const float* __restrict__ phi_prev, const float* __restrict__ x2,
    float* __restrict__ out) {
    __shared__ float2 hred2[8];
    __shared__ float4 hred4[8];
    __shared__ float  cbc[8];
    __shared__ float2 xs[128];
    __shared__ float2 sred[256];

    const float2* wT = (const float2*)(ws_ro + WS_WT);
    const float*  Hp = ws_ro + WS_PART;

    int bid = blockIdx.x, tid = threadIdx.x;
    int b = bid >> 1;                 // batch
    int jhb = bid & 1;                // j-half: 0 -> j 0..127, 1 -> j 128..255
    int lane = tid & 63, wid = tid >> 6;

    // x slice for this block's j-window
    if (tid < 256) ((float*)xs)[tid] = x2[b * (N_ * 2) + jhb * 256 + tid];

    // ---- head: h = sum_s Hp[s][b] + b1 (2 elements/thread) ----
    float2 b12 = *(const float2*)&b1[tid * 2];
    float h0 = b12.x, h1 = b12.y;
#pragma unroll
    for (int s = 0; s < SPLITS; ++s) {
        float2 p = *(const float2*)&Hp[(size_t)s * (B_ * DM) + b * DM + tid * 2];
        h0 += p.x; h1 += p.y;
    }
    float s1v = h0 + h1, s2v = h0 * h0 + h1 * h1;
#pragma unroll
    for (int off = 32; off > 0; off >>= 1) {
        s1v += __shfl_down(s1v, off);
        s2v += __shfl_down(s2v, off);
    }
    if (lane == 0) hred2[wid] = make_float2(s1v, s2v);
    __syncthreads();
    float ms = 0.f, vs = 0.f;
#pragma unroll
    for (int w = 0; w < 8; ++w) { ms += hred2[w].x; vs += hred2[w].y; }
    float mean = ms * (1.f / DM);
    float var  = vs * (1.f / DM) - mean * mean;
    float rstd = rsqrtf(var + 1e-5f);

    float2 g2  = *(const float2*)&lg[tid * 2];
    float2 be2 = *(const float2*)&lb[tid * 2];
    float y0 = fmaxf((h0 - mean) * rstd * g2.x + be2.x, 0.f);
    float y1 = fmaxf((h1 - mean) * rstd * g2.y + be2.y, 0.f);
    float4 wA = *(const float4*)&W2[(tid * 2) * 4];
    float4 wB = *(const float4*)&W2[(tid * 2 + 1) * 4];
    float4 pv;
    pv.x = y0 * wA.x + y1 * wB.x;
    pv.y = y0 * wA.y + y1 * wB.y;
    pv.z = y0 * wA.z + y1 * wB.z;
    pv.w = y0 * wA.w + y1 * wB.w;
#pragma unroll
    for (int off = 32; off > 0; off >>= 1) {
        pv.x += __shfl_down(pv.x, off);
        pv.y += __shfl_down(pv.y, off);
        pv.z += __shfl_down(pv.z, off);
        pv.w += __shfl_down(pv.w, off);
    }
    if (lane == 0) hred4[wid] = pv;
    __syncthreads();
    if (tid == 0) {
        float P0 = b2[0], P1 = b2[1], P2 = b2[2], P3 = b2[3];
#pragma unroll
        for (int w = 0; w < 8; ++w) {
            float4 o = hred4[w];
            P0 += o.x; P1 += o.y; P2 += o.z; P3 += o.w;
        }
        float dphi0 = tanhf(P0) * PI24;
        float dphi1 = tanhf(P2) * PI24;
        float phi0 = phi_prev[b * 2 + 0] + dphi0;
        float phi1 = phi_prev[b * 2 + 1] + dphi1;
        float r0 = 1.f / (1.f + expf(-P1));
        float r1 = 1.f / (1.f + expf(-P3));
        // both j-half blocks compute identical values; duplicate store benign
        out[B_ * N_ * 2 + b * 2 + 0] = phi0;
        out[B_ * N_ * 2 + b * 2 + 1] = phi1;
        out[B_ * N_ * 2 + B_ * 2 + b * 2 + 0] = dphi0;
        out[B_ * N_ * 2 + B_ * 2 + b * 2 + 1] = dphi1;
        cbc[0] = phi0 - phi1;   // delta
        cbc[1] = r1;
        cbc[2] = r0 - r1;       // dr
        cbc[3] = cosf(phi1);
        cbc[4] = sinf(phi1);
    }
    __syncthreads();
    float delta = cbc[0], r1v = cbc[1], drv = cbc[2], c1 = cbc[3], sn1 = cbc[4];

    // ---- main: i = tid&255, jq = tid>>8 (64 j each within this j-half) ----
    int i = tid & 255, jq = tid >> 8;
    int jloc = jq * 64;
    const float2* wp = &wT[(jhb * 128 + jloc) * N_ + i];

    float ar0 = 0.f, ai0 = 0.f, ar1 = 0.f, ai1 = 0.f;
#pragma unroll 4
    for (int jj = 0; jj < 64; jj += 2) {
        {
            float2 w = wp[(size_t)jj * N_];
            float r = fmaf(w.x, drv, r1v);
            float g = r * w.y;                       // in (0, 0.4)
            float u = g * g;
            // 1.1*tanh(g) ~= g*(1.1 + u*(-1.1/3 + u*2.2/15)), |err|<1e-4
            float tp = fmaf(u, fmaf(u, 0.14666667f, -0.36666667f), 1.1f);
            float A = g * tp;
            float ang = w.x * delta;
            float sn = __sinf(ang);
            float cs = __cosf(ang);
            float2 xv = xs[jloc + jj];
            float ar = A * cs, as_ = A * sn;
            ar0 = fmaf(ar, xv.x, ar0); ar0 = fmaf(-as_, xv.y, ar0);
            ai0 = fmaf(as_, xv.x, ai0); ai0 = fmaf(ar, xv.y, ai0);
        }
        {
            float2 w = wp[(size_t)(jj + 1) * N_];
            float r = fmaf(w.x, drv, r1v);
            float g = r * w.y;
            float u = g * g;
            float tp = fmaf(u, fmaf(u, 0.14666667f, -0.36666667f), 1.1f);
            float A = g * tp;
            float ang = w.x * delta;
            float sn = __sinf(ang);
            float cs = __cosf(ang);
            float2 xv = xs[jloc + jj + 1];
            float ar = A * cs, as_ = A * sn;
            ar1 = fmaf(ar, xv.x, ar1); ar1 = fmaf(-as_, xv.y, ar1);
            ai1 = fmaf(as_, xv.x, ai1); ai1 = fmaf(ar, xv.y, ai1);
        }
    }
    float accr = ar0 + ar1, acci = ai0 + ai1;
    if (jq) sred[i] = make_float2(accr, acci);
    __syncthreads();
    if (!jq) {
        float2 o = sred[i];
        accr += o.x; acci += o.y;
        float outr = c1 * accr - sn1 * acci;
        float outi = sn1 * accr + c1 * acci;
        // combine the two j-half blocks (exactly 2 commutative adds on 0)
        atomicAdd(&out[(b * N_ + i) * 2],     outr);
        atomicAdd(&out[(b * N_ + i) * 2 + 1], outi);
    }
}

// ---------------------------------------------------------------------------
extern "C" void kernel_launch(void* const* d_in, const int* in_sizes, int n_in,
                              void* d_out, int out_size, void* d_ws, size_t ws_size,
                              hipStream_t stream) {
    const float* x_2ch    = (const float*)d_in[0];
    const float* history  = (const float*)d_in[1];
    const float* phi_prev = (const float*)d_in[2];
    const float* S        = (const float*)d_in[3];
    const float* W1       = (const float*)d_in[4];
    const float* b1       = (const float*)d_in[5];
    const float* ln_g     = (const float*)d_in[6];
    const float* ln_b     = (const float*)d_in[7];
    const float* W2       = (const float*)d_in[8];
    const float* b2       = (const float*)d_in[9];
    const float* path_w   = (const float*)d_in[10];

    float* out = (float*)d_out;
    float* ws  = (float*)d_ws;

    k1_gemm_prep<<<256, 512, 0, stream>>>(history, W1, path_w, S, ws, out);
    k2_head_main<<<512, 512, 0, stream>>>(ws, b1, ln_g, ln_b, W2, b2,
                                          phi_prev, x_2ch, out);
}